// Round 5
// baseline (172.472 us; speedup 1.0000x reference)
//
#include <hip/hip_runtime.h>

// ---------------------------------------------------------------------------
// Compile-time Cayley tables for PGA G(3,0,1), basis ordered by grade:
// idx: 0:1 1:e0 2:e1 3:e2 4:e3 5:e01 6:e02 7:e03 8:e12 9:e13 10:e23
//      11:e012 12:e013 13:e023 14:e123 15:e0123
// Blade as 4-bit mask: e0=bit0, e1=bit1, e2=bit2, e3=bit3.
// ---------------------------------------------------------------------------
namespace ga {

constexpr int MASK[16]        = {0,1,2,4,8,3,5,9,6,10,12,7,11,13,14,15};
constexpr int IDX_OF_MASK[16] = {0,1,2,5,3,6,8,11,4,7,9,12,10,13,14,15};

constexpr int popc(int v) { int c = 0; while (v) { c += v & 1; v >>= 1; } return c; }

constexpr int reorder_sign(int a, int b) {
    int s = 0; int t = a >> 1;
    while (t) { s += popc(t & b); t >>= 1; }
    return (s & 1) ? -1 : 1;
}

struct Term { signed char i, j, k, s; };

// Geometric product, metric (0,1,1,1): 192 nonzero terms.
struct GPTab { Term t[192]; };
constexpr GPTab build_gp() {
    GPTab T{}; int n = 0;
    for (int i = 0; i < 16; i++)
        for (int j = 0; j < 16; j++) {
            int a = MASK[i], b = MASK[j];
            if (a & b & 1) continue;                 // e0^2 = 0
            T.t[n].i = (signed char)i;
            T.t[n].j = (signed char)j;
            T.t[n].k = (signed char)IDX_OF_MASK[a ^ b];
            T.t[n].s = (signed char)reorder_sign(a, b);
            n++;
        }
    return T;
}

// Join (sans ref scale): dual(dual(x) ^ dual(y)) folded to 81 terms.
struct JNTab { Term t[81]; };
constexpr JNTab build_join() {
    JNTab T{}; int n = 0;
    int didx[16] = {}, dsgn[16] = {};
    for (int i = 0; i < 16; i++) {
        int a = MASK[i], c = (~a) & 0xF;
        didx[i] = IDX_OF_MASK[c];
        dsgn[i] = reorder_sign(a, c);
    }
    for (int i = 0; i < 16; i++)
        for (int j = 0; j < 16; j++) {
            int p = didx[i], q = didx[j];
            int a = MASK[p], b = MASK[q];
            if (a & b) continue;
            int m = IDX_OF_MASK[a | b];
            int k = didx[m];
            int s = dsgn[i] * dsgn[j] * dsgn[m] * reorder_sign(a, b);
            T.t[n].i = (signed char)i;
            T.t[n].j = (signed char)j;
            T.t[n].k = (signed char)k;
            T.t[n].s = (signed char)s;
            n++;
        }
    return T;
}

constexpr GPTab G = build_gp();
constexpr JNTab J = build_join();

} // namespace ga

// ---------------------------------------------------------------------------
// R5: persistent single-wave workgroups + register-prefetch pipeline.
//
// R4 post-mortem: two different kernels (R2 strided, R4 LDS-coalesced) both
// pin at ~3.2-3.3 TB/s logical with all pipes <30% busy — latency/structure
// bound, not pattern bound. One-shot blocks keep loads in flight only ~1/3 of
// wave lifetime. Fix: each wave owns NITER=4 consecutive 64-pt chunks and
// prefetches chunk i+1 into registers while computing chunk i.
//
// No __syncthreads(): it drains vmcnt(0) and would serialize the prefetch
// (m97 lesson). Blocks are one wave; LDS is wave-private; the HW LDS pipe is
// in-order per wave (validated by R4's barrier-free stage->read). The two
// PROVABLY per-thread-disjoint LDS hazards (R3 bug class):
//   (1) lo-overlay writes vs lx/ly frag reads,
//   (2) next-iter staging writes vs this-iter lo reads,
// are fenced with asm volatile("":::"memory") — a compiler-only fence
// (mayLoad/mayStore in MIR, nothing emitted, no waitcnt) that pins
// instruction order; HW in-order execution does the rest.
//
// LDS per wave (floats): lx[64][20] | ly[64][20]  (2560 = 10 KB)
//   stride 20 (80 B): b128 ops process 8 lanes/phase; 8 lanes x 16 B tile all
//   32 banks -> conflict-free (R4: 96 conflict-cyc/wave, from 2-way staging).
//   out overlay lo[64][36] (2304 <= 2560), same 8-lane-phase analysis: free.
// ref: direct per-lane scalar load of [16p+15] (same HBM sectors as float4).
// ---------------------------------------------------------------------------
constexpr int XSTRIDE = 20;
constexpr int OSTRIDE = 36;

__global__ __launch_bounds__(64)
void MVGeometricBilinear_kernel(const float* __restrict__ x,
                                const float* __restrict__ y,
                                const float* __restrict__ ref,
                                float* __restrict__ out,
                                int nchunks, int niter)
{
    __shared__ __align__(16) float lds[64 * XSTRIDE * 2];   // 10 KB

    const int lane = threadIdx.x;          // block == 1 wave
    long chunk = (long)blockIdx.x * niter;
    long cend  = chunk + niter;
    if (cend > nchunks) cend = nchunks;
    if (chunk >= cend) return;

    float* lx = lds;                        // [64][20]
    float* ly = lds + 64 * XSTRIDE;         // [64][20]
    float* lo = lds;                        // [64][36] overlay

    // ---- prologue: load chunk 0 into registers ----
    float4 cx[4], cy[4]; float cr;
    {
        const float4* gx = reinterpret_cast<const float4*>(x) + chunk * 256;
        const float4* gy = reinterpret_cast<const float4*>(y) + chunk * 256;
#pragma unroll
        for (int c = 0; c < 4; c++) { cx[c] = gx[lane + 64*c]; cy[c] = gy[lane + 64*c]; }
        cr = ref[(chunk * 64 + lane) * 16 + 15];
    }

    while (true) {
        // ---- stage current chunk regs -> LDS (transpose) ----
        // stage->frag-read order is compiler-preserved: each stage-write instr
        // may-alias some frag read per-thread (verified per (c,k) pair).
#pragma unroll
        for (int c = 0; c < 4; c++) {
            const int p  = 16*c + (lane >> 2);
            const int ch = lane & 3;
            *reinterpret_cast<float4*>(lx + p * XSTRIDE + ch * 4) = cx[c];
            *reinterpret_cast<float4*>(ly + p * XSTRIDE + ch * 4) = cy[c];
        }
        const float r = cr;

        // ---- prefetch next chunk (in flight across compute; no waits here) ----
        const long next = chunk + 1;
        const bool pf = (next < cend);      // wave-uniform
        float4 nx[4], ny[4]; float nr = 0.f;
        if (pf) {
            const float4* gx = reinterpret_cast<const float4*>(x) + next * 256;
            const float4* gy = reinterpret_cast<const float4*>(y) + next * 256;
#pragma unroll
            for (int c = 0; c < 4; c++) { nx[c] = gx[lane + 64*c]; ny[c] = gy[lane + 64*c]; }
            nr = ref[(next * 64 + lane) * 16 + 15];
        }

        // ---- fragments: conflict-free b128 LDS reads (lane-stride 80 B) ----
        float xx[16], yy[16];
#pragma unroll
        for (int k = 0; k < 4; k++) {
            const float4 vx = *reinterpret_cast<const float4*>(lx + lane * XSTRIDE + k * 4);
            const float4 vy = *reinterpret_cast<const float4*>(ly + lane * XSTRIDE + k * 4);
            xx[4*k+0] = vx.x; xx[4*k+1] = vx.y; xx[4*k+2] = vx.z; xx[4*k+3] = vx.w;
            yy[4*k+0] = vy.x; yy[4*k+1] = vy.y; yy[4*k+2] = vy.z; yy[4*k+3] = vy.w;
        }

        // ---- compute ----
        float gp[16] = {0.f, 0.f, 0.f, 0.f, 0.f, 0.f, 0.f, 0.f,
                        0.f, 0.f, 0.f, 0.f, 0.f, 0.f, 0.f, 0.f};
        float jn[16] = {0.f, 0.f, 0.f, 0.f, 0.f, 0.f, 0.f, 0.f,
                        0.f, 0.f, 0.f, 0.f, 0.f, 0.f, 0.f, 0.f};
#pragma unroll
        for (int t = 0; t < 192; t++) {
            const int ti = ga::G.t[t].i, tj = ga::G.t[t].j, tk = ga::G.t[t].k;
            const float v = xx[ti] * yy[tj];
            if (ga::G.t[t].s > 0) gp[tk] += v; else gp[tk] -= v;
        }
#pragma unroll
        for (int t = 0; t < 81; t++) {
            const int ti = ga::J.t[t].i, tj = ga::J.t[t].j, tk = ga::J.t[t].k;
            const float v = xx[ti] * yy[tj];
            if (ga::J.t[t].s > 0) jn[tk] += v; else jn[tk] -= v;
        }

        // Fence #1: frag reads stay above, lo-overlay writes stay below.
        asm volatile("" ::: "memory");

        // ---- stage results into overlay ----
#pragma unroll
        for (int k = 0; k < 4; k++)
            *reinterpret_cast<float4*>(lo + lane * OSTRIDE + k * 4) =
                make_float4(gp[4*k+0], gp[4*k+1], gp[4*k+2], gp[4*k+3]);
#pragma unroll
        for (int k = 0; k < 4; k++)
            *reinterpret_cast<float4*>(lo + lane * OSTRIDE + 16 + k * 4) =
                make_float4(r * jn[4*k+0], r * jn[4*k+1], r * jn[4*k+2], r * jn[4*k+3]);

        // ---- cooperative unit-stride store: 512 float4 per chunk ----
        float4* go = reinterpret_cast<float4*>(out) + chunk * 512;
#pragma unroll
        for (int c = 0; c < 8; c++) {
            const int g  = lane + 64 * c;
            const int p  = g >> 3;
            const int ch = g & 7;
            go[g] = *reinterpret_cast<const float4*>(lo + p * OSTRIDE + ch * 4);
        }

        // Fence #2: lo reads stay above, next-iter staging writes stay below.
        asm volatile("" ::: "memory");

        if (!pf) break;
#pragma unroll
        for (int c = 0; c < 4; c++) { cx[c] = nx[c]; cy[c] = ny[c]; }
        cr = nr;
        chunk = next;
    }
}

// Tail path (npts not divisible by 64) — scalar per-thread, same math.
__global__ __launch_bounds__(64)
void MVGeometricBilinear_tail(const float* __restrict__ x,
                              const float* __restrict__ y,
                              const float* __restrict__ ref,
                              float* __restrict__ out,
                              int start, int npts)
{
    int pt = start + blockIdx.x * 64 + threadIdx.x;
    if (pt >= npts) return;
    float xx[16], yy[16];
#pragma unroll
    for (int k = 0; k < 16; k++) { xx[k] = x[(size_t)pt*16+k]; yy[k] = y[(size_t)pt*16+k]; }
    const float r = ref[(size_t)pt*16+15];
    float gp[16] = {}, jn[16] = {};
#pragma unroll
    for (int t = 0; t < 192; t++) {
        const float v = xx[ga::G.t[t].i] * yy[ga::G.t[t].j];
        if (ga::G.t[t].s > 0) gp[ga::G.t[t].k] += v; else gp[ga::G.t[t].k] -= v;
    }
#pragma unroll
    for (int t = 0; t < 81; t++) {
        const float v = xx[ga::J.t[t].i] * yy[ga::J.t[t].j];
        if (ga::J.t[t].s > 0) jn[ga::J.t[t].k] += v; else jn[ga::J.t[t].k] -= v;
    }
#pragma unroll
    for (int k = 0; k < 16; k++) out[(size_t)pt*32+k] = gp[k];
#pragma unroll
    for (int k = 0; k < 16; k++) out[(size_t)pt*32+16+k] = r * jn[k];
}

extern "C" void kernel_launch(void* const* d_in, const int* in_sizes, int n_in,
                              void* d_out, int out_size, void* d_ws, size_t ws_size,
                              hipStream_t stream) {
    const float* x   = (const float*)d_in[0];
    const float* y   = (const float*)d_in[1];
    const float* ref = (const float*)d_in[2];
    float* out = (float*)d_out;

    const int npts    = in_sizes[0] / 16;     // B*T = 524288
    const int nchunks = npts / 64;            // 8192
    const int niter   = 4;                    // chunks per wave
    const int blocks  = (nchunks + niter - 1) / niter;   // 2048

    if (nchunks > 0) {
        MVGeometricBilinear_kernel<<<blocks, 64, 0, stream>>>(
            x, y, ref, out, nchunks, niter);
    }

    const int rem = npts - nchunks * 64;      // 0 for this shape
    if (rem > 0) {
        MVGeometricBilinear_tail<<<(rem + 63) / 64, 64, 0, stream>>>(
            x, y, ref, out, nchunks * 64, npts);
    }
}

// Round 6
// 170.985 us; speedup vs baseline: 1.0087x; 1.0087x over previous
//
#include <hip/hip_runtime.h>

// ---------------------------------------------------------------------------
// Compile-time Cayley tables for PGA G(3,0,1), basis ordered by grade:
// idx: 0:1 1:e0 2:e1 3:e2 4:e3 5:e01 6:e02 7:e03 8:e12 9:e13 10:e23
//      11:e012 12:e013 13:e023 14:e123 15:e0123
// Blade as 4-bit mask: e0=bit0, e1=bit1, e2=bit2, e3=bit3.
// ---------------------------------------------------------------------------
namespace ga {

constexpr int MASK[16]        = {0,1,2,4,8,3,5,9,6,10,12,7,11,13,14,15};
constexpr int IDX_OF_MASK[16] = {0,1,2,5,3,6,8,11,4,7,9,12,10,13,14,15};

constexpr int popc(int v) { int c = 0; while (v) { c += v & 1; v >>= 1; } return c; }

constexpr int reorder_sign(int a, int b) {
    int s = 0; int t = a >> 1;
    while (t) { s += popc(t & b); t >>= 1; }
    return (s & 1) ? -1 : 1;
}

struct Term { signed char i, j, k, s; };

// Geometric product, metric (0,1,1,1): 192 nonzero terms.
struct GPTab { Term t[192]; };
constexpr GPTab build_gp() {
    GPTab T{}; int n = 0;
    for (int i = 0; i < 16; i++)
        for (int j = 0; j < 16; j++) {
            int a = MASK[i], b = MASK[j];
            if (a & b & 1) continue;                 // e0^2 = 0
            T.t[n].i = (signed char)i;
            T.t[n].j = (signed char)j;
            T.t[n].k = (signed char)IDX_OF_MASK[a ^ b];
            T.t[n].s = (signed char)reorder_sign(a, b);
            n++;
        }
    return T;
}

// Join (sans ref scale): dual(dual(x) ^ dual(y)) folded to 81 terms.
struct JNTab { Term t[81]; };
constexpr JNTab build_join() {
    JNTab T{}; int n = 0;
    int didx[16] = {}, dsgn[16] = {};
    for (int i = 0; i < 16; i++) {
        int a = MASK[i], c = (~a) & 0xF;
        didx[i] = IDX_OF_MASK[c];
        dsgn[i] = reorder_sign(a, c);
    }
    for (int i = 0; i < 16; i++)
        for (int j = 0; j < 16; j++) {
            int p = didx[i], q = didx[j];
            int a = MASK[p], b = MASK[q];
            if (a & b) continue;
            int m = IDX_OF_MASK[a | b];
            int k = didx[m];
            int s = dsgn[i] * dsgn[j] * dsgn[m] * reorder_sign(a, b);
            T.t[n].i = (signed char)i;
            T.t[n].j = (signed char)j;
            T.t[n].k = (signed char)k;
            T.t[n].s = (signed char)s;
            n++;
        }
    return T;
}

constexpr GPTab G = build_gp();
constexpr JNTab J = build_join();

} // namespace ga

// ---------------------------------------------------------------------------
// R6 = R5 (persistent single-wave workgroups + register-prefetch pipeline)
// with the register allocator un-starved.
//
// R5 post-mortem: VGPR_Count=68 but live state across compute is ~110 VGPRs
// (nx/ny 32 + xx/yy 32 + gp/jn 32 + addrs) -> compiler spilled the prefetch
// to scratch every iteration. Evidence: WRITE_SIZE 65.5->180 MB, FETCH +34 MB
// with identical logical store traffic; hbm_gbps ROSE to 3.7 TB/s (pipeline
// works!) but the bandwidth was spent on spill traffic.
// Fix: __launch_bounds__(64, 2). Grid gives 8 one-wave blocks/CU = 2
// waves/EU, so min-2-waves costs no occupancy and raises the VGPR cap to
// ~256 -> no spills.
//
// No __syncthreads() (vmcnt(0) drain would serialize the prefetch — m97
// lesson). Wave-private LDS, in-order LDS pipe per wave. The two provably
// per-thread-disjoint LDS hazards (R3 bug class) are pinned with
// asm volatile("":::"memory") compiler fences (no instruction emitted).
//
// LDS per wave (floats): lx[64][20] | ly[64][20]  (2560 = 10 KB)
//   stride 20 (80 B): b128 ops process 8 lanes/phase; 8 lanes x 16 B tile all
//   32 banks -> conflict-free. out overlay lo[64][36] (2304 <= 2560): free.
// ---------------------------------------------------------------------------
constexpr int XSTRIDE = 20;
constexpr int OSTRIDE = 36;

__global__ __launch_bounds__(64, 2)   // min 2 waves/EU -> VGPR cap ~256, no spill
void MVGeometricBilinear_kernel(const float* __restrict__ x,
                                const float* __restrict__ y,
                                const float* __restrict__ ref,
                                float* __restrict__ out,
                                int nchunks, int niter)
{
    __shared__ __align__(16) float lds[64 * XSTRIDE * 2];   // 10 KB

    const int lane = threadIdx.x;          // block == 1 wave
    long chunk = (long)blockIdx.x * niter;
    long cend  = chunk + niter;
    if (cend > nchunks) cend = nchunks;
    if (chunk >= cend) return;

    float* lx = lds;                        // [64][20]
    float* ly = lds + 64 * XSTRIDE;         // [64][20]
    float* lo = lds;                        // [64][36] overlay

    // ---- prologue: load chunk 0 into registers ----
    float4 cx[4], cy[4]; float cr;
    {
        const float4* gx = reinterpret_cast<const float4*>(x) + chunk * 256;
        const float4* gy = reinterpret_cast<const float4*>(y) + chunk * 256;
#pragma unroll
        for (int c = 0; c < 4; c++) { cx[c] = gx[lane + 64*c]; cy[c] = gy[lane + 64*c]; }
        cr = ref[(chunk * 64 + lane) * 16 + 15];
    }

    while (true) {
        // ---- stage current chunk regs -> LDS (transpose) ----
        // stage->frag-read order is compiler-preserved: each stage-write instr
        // may-alias some frag read per-thread.
#pragma unroll
        for (int c = 0; c < 4; c++) {
            const int p  = 16*c + (lane >> 2);
            const int ch = lane & 3;
            *reinterpret_cast<float4*>(lx + p * XSTRIDE + ch * 4) = cx[c];
            *reinterpret_cast<float4*>(ly + p * XSTRIDE + ch * 4) = cy[c];
        }
        const float r = cr;

        // ---- prefetch next chunk (in flight across compute) ----
        const long next = chunk + 1;
        const bool pf = (next < cend);      // wave-uniform
        float4 nx[4], ny[4]; float nr = 0.f;
        if (pf) {
            const float4* gx = reinterpret_cast<const float4*>(x) + next * 256;
            const float4* gy = reinterpret_cast<const float4*>(y) + next * 256;
#pragma unroll
            for (int c = 0; c < 4; c++) { nx[c] = gx[lane + 64*c]; ny[c] = gy[lane + 64*c]; }
            nr = ref[(next * 64 + lane) * 16 + 15];
        }

        // ---- fragments: conflict-free b128 LDS reads (lane-stride 80 B) ----
        float xx[16], yy[16];
#pragma unroll
        for (int k = 0; k < 4; k++) {
            const float4 vx = *reinterpret_cast<const float4*>(lx + lane * XSTRIDE + k * 4);
            const float4 vy = *reinterpret_cast<const float4*>(ly + lane * XSTRIDE + k * 4);
            xx[4*k+0] = vx.x; xx[4*k+1] = vx.y; xx[4*k+2] = vx.z; xx[4*k+3] = vx.w;
            yy[4*k+0] = vy.x; yy[4*k+1] = vy.y; yy[4*k+2] = vy.z; yy[4*k+3] = vy.w;
        }

        // ---- compute ----
        float gp[16] = {0.f, 0.f, 0.f, 0.f, 0.f, 0.f, 0.f, 0.f,
                        0.f, 0.f, 0.f, 0.f, 0.f, 0.f, 0.f, 0.f};
        float jn[16] = {0.f, 0.f, 0.f, 0.f, 0.f, 0.f, 0.f, 0.f,
                        0.f, 0.f, 0.f, 0.f, 0.f, 0.f, 0.f, 0.f};
#pragma unroll
        for (int t = 0; t < 192; t++) {
            const int ti = ga::G.t[t].i, tj = ga::G.t[t].j, tk = ga::G.t[t].k;
            const float v = xx[ti] * yy[tj];
            if (ga::G.t[t].s > 0) gp[tk] += v; else gp[tk] -= v;
        }
#pragma unroll
        for (int t = 0; t < 81; t++) {
            const int ti = ga::J.t[t].i, tj = ga::J.t[t].j, tk = ga::J.t[t].k;
            const float v = xx[ti] * yy[tj];
            if (ga::J.t[t].s > 0) jn[tk] += v; else jn[tk] -= v;
        }

        // Fence #1: frag reads stay above, lo-overlay writes stay below.
        asm volatile("" ::: "memory");

        // ---- stage results into overlay ----
#pragma unroll
        for (int k = 0; k < 4; k++)
            *reinterpret_cast<float4*>(lo + lane * OSTRIDE + k * 4) =
                make_float4(gp[4*k+0], gp[4*k+1], gp[4*k+2], gp[4*k+3]);
#pragma unroll
        for (int k = 0; k < 4; k++)
            *reinterpret_cast<float4*>(lo + lane * OSTRIDE + 16 + k * 4) =
                make_float4(r * jn[4*k+0], r * jn[4*k+1], r * jn[4*k+2], r * jn[4*k+3]);

        // ---- cooperative unit-stride store: 512 float4 per chunk ----
        float4* go = reinterpret_cast<float4*>(out) + chunk * 512;
#pragma unroll
        for (int c = 0; c < 8; c++) {
            const int g  = lane + 64 * c;
            const int p  = g >> 3;
            const int ch = g & 7;
            go[g] = *reinterpret_cast<const float4*>(lo + p * OSTRIDE + ch * 4);
        }

        // Fence #2: lo reads stay above, next-iter staging writes stay below.
        asm volatile("" ::: "memory");

        if (!pf) break;
#pragma unroll
        for (int c = 0; c < 4; c++) { cx[c] = nx[c]; cy[c] = ny[c]; }
        cr = nr;
        chunk = next;
    }
}

// Tail path (npts not divisible by 64) — scalar per-thread, same math.
__global__ __launch_bounds__(64)
void MVGeometricBilinear_tail(const float* __restrict__ x,
                              const float* __restrict__ y,
                              const float* __restrict__ ref,
                              float* __restrict__ out,
                              int start, int npts)
{
    int pt = start + blockIdx.x * 64 + threadIdx.x;
    if (pt >= npts) return;
    float xx[16], yy[16];
#pragma unroll
    for (int k = 0; k < 16; k++) { xx[k] = x[(size_t)pt*16+k]; yy[k] = y[(size_t)pt*16+k]; }
    const float r = ref[(size_t)pt*16+15];
    float gp[16] = {}, jn[16] = {};
#pragma unroll
    for (int t = 0; t < 192; t++) {
        const float v = xx[ga::G.t[t].i] * yy[ga::G.t[t].j];
        if (ga::G.t[t].s > 0) gp[ga::G.t[t].k] += v; else gp[ga::G.t[t].k] -= v;
    }
#pragma unroll
    for (int t = 0; t < 81; t++) {
        const float v = xx[ga::J.t[t].i] * yy[ga::J.t[t].j];
        if (ga::J.t[t].s > 0) jn[ga::J.t[t].k] += v; else jn[ga::J.t[t].k] -= v;
    }
#pragma unroll
    for (int k = 0; k < 16; k++) out[(size_t)pt*32+k] = gp[k];
#pragma unroll
    for (int k = 0; k < 16; k++) out[(size_t)pt*32+16+k] = r * jn[k];
}

extern "C" void kernel_launch(void* const* d_in, const int* in_sizes, int n_in,
                              void* d_out, int out_size, void* d_ws, size_t ws_size,
                              hipStream_t stream) {
    const float* x   = (const float*)d_in[0];
    const float* y   = (const float*)d_in[1];
    const float* ref = (const float*)d_in[2];
    float* out = (float*)d_out;

    const int npts    = in_sizes[0] / 16;     // B*T = 524288
    const int nchunks = npts / 64;            // 8192
    const int niter   = 4;                    // chunks per wave
    const int blocks  = (nchunks + niter - 1) / niter;   // 2048

    if (nchunks > 0) {
        MVGeometricBilinear_kernel<<<blocks, 64, 0, stream>>>(
            x, y, ref, out, nchunks, niter);
    }

    const int rem = npts - nchunks * 64;      // 0 for this shape
    if (rem > 0) {
        MVGeometricBilinear_tail<<<(rem + 63) / 64, 64, 0, stream>>>(
            x, y, ref, out, nchunks * 64, npts);
    }
}

// Round 7
// 145.940 us; speedup vs baseline: 1.1818x; 1.1716x over previous
//
#include <hip/hip_runtime.h>

// ---------------------------------------------------------------------------
// Compile-time Cayley tables for PGA G(3,0,1), basis ordered by grade:
// idx: 0:1 1:e0 2:e1 3:e2 4:e3 5:e01 6:e02 7:e03 8:e12 9:e13 10:e23
//      11:e012 12:e013 13:e023 14:e123 15:e0123
// Blade as 4-bit mask: e0=bit0, e1=bit1, e2=bit2, e3=bit3.
// ---------------------------------------------------------------------------
namespace ga {

constexpr int MASK[16]        = {0,1,2,4,8,3,5,9,6,10,12,7,11,13,14,15};
constexpr int IDX_OF_MASK[16] = {0,1,2,5,3,6,8,11,4,7,9,12,10,13,14,15};

constexpr int popc(int v) { int c = 0; while (v) { c += v & 1; v >>= 1; } return c; }

constexpr int reorder_sign(int a, int b) {
    int s = 0; int t = a >> 1;
    while (t) { s += popc(t & b); t >>= 1; }
    return (s & 1) ? -1 : 1;
}

struct Term { signed char i, j, k, s; };

// Geometric product, metric (0,1,1,1): 192 nonzero terms.
struct GPTab { Term t[192]; };
constexpr GPTab build_gp() {
    GPTab T{}; int n = 0;
    for (int i = 0; i < 16; i++)
        for (int j = 0; j < 16; j++) {
            int a = MASK[i], b = MASK[j];
            if (a & b & 1) continue;                 // e0^2 = 0
            T.t[n].i = (signed char)i;
            T.t[n].j = (signed char)j;
            T.t[n].k = (signed char)IDX_OF_MASK[a ^ b];
            T.t[n].s = (signed char)reorder_sign(a, b);
            n++;
        }
    return T;
}

// Join (sans ref scale): dual(dual(x) ^ dual(y)) folded to 81 terms.
struct JNTab { Term t[81]; };
constexpr JNTab build_join() {
    JNTab T{}; int n = 0;
    int didx[16] = {}, dsgn[16] = {};
    for (int i = 0; i < 16; i++) {
        int a = MASK[i], c = (~a) & 0xF;
        didx[i] = IDX_OF_MASK[c];
        dsgn[i] = reorder_sign(a, c);
    }
    for (int i = 0; i < 16; i++)
        for (int j = 0; j < 16; j++) {
            int p = didx[i], q = didx[j];
            int a = MASK[p], b = MASK[q];
            if (a & b) continue;
            int m = IDX_OF_MASK[a | b];
            int k = didx[m];
            int s = dsgn[i] * dsgn[j] * dsgn[m] * reorder_sign(a, b);
            T.t[n].i = (signed char)i;
            T.t[n].j = (signed char)j;
            T.t[n].k = (signed char)k;
            T.t[n].s = (signed char)s;
            n++;
        }
    return T;
}

constexpr GPTab G = build_gp();
constexpr JNTab J = build_join();

} // namespace ga

// ---------------------------------------------------------------------------
// R7: double-buffered LDS pipeline via global_load_lds DMA (no VGPR staging).
//
// R5/R6 post-mortem: register prefetch raised hbm to 3.7 TB/s (pipeline
// validated) but the ~110-VGPR live set got spilled to scratch (VGPR_Count
// stuck at 68 regardless of __launch_bounds__; WRITE_SIZE 65.5 -> 180 MB of
// pure spill traffic). Fix: prefetch straight into LDS with
// __builtin_amdgcn_global_load_lds — zero destination VGPRs, so the compute
// live set (~75 regs) fits and spills are impossible by construction.
//
// Per iteration (chunk i in buffer cur):
//   1. issue 9 DMA ops for chunk i+1 into buffer cur^1
//   2. s_waitcnt vmcnt(9): oldest-first drain through chunk i's 9 DMAs
//      (m135 semantics); i+1's DMA stays IN FLIGHT across compute — the
//      never-drain-to-zero-midstream pattern. Last iter: vmcnt(0).
//   3. frag b128 reads from cur (DMA layout is unpadded point-major 64 B
//      stride -> 4-way bank conflict, ~1.6x on 8 LDS instrs — accepted;
//      DMA's wave-uniform-base+lane*16 rule forbids padding)
//   4. compute; fence; stage results in 36-stride overlay over cur
//      (conflict-free, R4/R5-validated); unit-stride float4 stores.
// Buffer A is never touched while its DMA is in flight (compute works on B).
// No __syncthreads anywhere (single-wave blocks, wave-private LDS).
//
// LDS: 2 x 2304 floats (x[1024]|y[1024], lo overlay spans 2304) + 2 x 64
// ref floats = 18.9 KB -> 8 blocks/CU; grid 2048 = exactly 8/CU, persistent.
// ---------------------------------------------------------------------------
constexpr int BUF_FLOATS = 2304;   // 9 KB per buffer
constexpr int OSTRIDE    = 36;

typedef const __attribute__((address_space(1))) void* gas_ptr;
typedef __attribute__((address_space(3))) void*       las_ptr;

__global__ __launch_bounds__(64, 2)
void MVGeometricBilinear_kernel(const float* __restrict__ x,
                                const float* __restrict__ y,
                                const float* __restrict__ ref,
                                float* __restrict__ out,
                                int nchunks, int niter)
{
    __shared__ __align__(16) float buf[2][BUF_FLOATS];
    __shared__ __align__(16) float rbuf[2][64];

    const int lane = threadIdx.x;          // block == 1 wave
    long chunk = (long)blockIdx.x * niter;
    long cend  = chunk + niter;
    if (cend > nchunks) cend = nchunks;
    if (chunk >= cend) return;

    // 9 DMA ops: x -> buf[b][0..1023], y -> buf[b][1024..2047], ref -> rbuf[b].
    // Op k, lane L lands at base + L*16 B => float4 index k*64+L == global index.
    auto dma_chunk = [&](long c, int b) {
        const float4* gx = reinterpret_cast<const float4*>(x) + c * 256;
        const float4* gy = reinterpret_cast<const float4*>(y) + c * 256;
#pragma unroll
        for (int k = 0; k < 4; k++) {
            __builtin_amdgcn_global_load_lds((gas_ptr)(gx + k * 64 + lane),
                                             (las_ptr)(&buf[b][k * 256]), 16, 0, 0);
            __builtin_amdgcn_global_load_lds((gas_ptr)(gy + k * 64 + lane),
                                             (las_ptr)(&buf[b][1024 + k * 256]), 16, 0, 0);
        }
        __builtin_amdgcn_global_load_lds((gas_ptr)(ref + (c * 64 + lane) * 16 + 15),
                                         (las_ptr)(&rbuf[b][0]), 4, 0, 0);
    };

    int cur = 0;
    dma_chunk(chunk, 0);                   // prologue: chunk 0 -> buffer A

    while (true) {
        const long next = chunk + 1;
        const bool pf = (next < cend);     // wave-uniform

        if (pf) {
            dma_chunk(next, cur ^ 1);      // i+1 in flight across compute of i
            // Outstanding (oldest first): [DMA i (9)] [stores i-1 (<=8)] [DMA i+1 (9)].
            // Wait: note stores i-1 were issued BEFORE DMA i+1 but AFTER DMA i —
            // actual queue order is DMA i, stores i-1, DMA i+1; vmcnt(9) drains
            // everything except the 9 newest = DMA i+1.  Chunk i data ready.
            asm volatile("s_waitcnt vmcnt(9)" ::: "memory");
        } else {
            asm volatile("s_waitcnt vmcnt(0)" ::: "memory");
        }

        // ---- fragments: b128 LDS reads, point-major 64 B stride ----
        const float* bx = &buf[cur][0];
        const float* by = &buf[cur][1024];
        float xx[16], yy[16];
#pragma unroll
        for (int k = 0; k < 4; k++) {
            const float4 vx = *reinterpret_cast<const float4*>(bx + lane * 16 + k * 4);
            const float4 vy = *reinterpret_cast<const float4*>(by + lane * 16 + k * 4);
            xx[4*k+0] = vx.x; xx[4*k+1] = vx.y; xx[4*k+2] = vx.z; xx[4*k+3] = vx.w;
            yy[4*k+0] = vy.x; yy[4*k+1] = vy.y; yy[4*k+2] = vy.z; yy[4*k+3] = vy.w;
        }
        const float r = rbuf[cur][lane];

        // ---- compute ----
        float gp[16] = {0.f, 0.f, 0.f, 0.f, 0.f, 0.f, 0.f, 0.f,
                        0.f, 0.f, 0.f, 0.f, 0.f, 0.f, 0.f, 0.f};
        float jn[16] = {0.f, 0.f, 0.f, 0.f, 0.f, 0.f, 0.f, 0.f,
                        0.f, 0.f, 0.f, 0.f, 0.f, 0.f, 0.f, 0.f};
#pragma unroll
        for (int t = 0; t < 192; t++) {
            const int ti = ga::G.t[t].i, tj = ga::G.t[t].j, tk = ga::G.t[t].k;
            const float v = xx[ti] * yy[tj];
            if (ga::G.t[t].s > 0) gp[tk] += v; else gp[tk] -= v;
        }
#pragma unroll
        for (int t = 0; t < 81; t++) {
            const int ti = ga::J.t[t].i, tj = ga::J.t[t].j, tk = ga::J.t[t].k;
            const float v = xx[ti] * yy[tj];
            if (ga::J.t[t].s > 0) jn[tk] += v; else jn[tk] -= v;
        }

        // Fence: frag reads stay above, lo-overlay writes stay below
        // (cross-lane WAR invisible to per-thread alias analysis — R3 lesson).
        asm volatile("" ::: "memory");

        // ---- stage results: 36-stride overlay over current buffer ----
        float* lo = &buf[cur][0];
#pragma unroll
        for (int k = 0; k < 4; k++)
            *reinterpret_cast<float4*>(lo + lane * OSTRIDE + k * 4) =
                make_float4(gp[4*k+0], gp[4*k+1], gp[4*k+2], gp[4*k+3]);
#pragma unroll
        for (int k = 0; k < 4; k++)
            *reinterpret_cast<float4*>(lo + lane * OSTRIDE + 16 + k * 4) =
                make_float4(r * jn[4*k+0], r * jn[4*k+1], r * jn[4*k+2], r * jn[4*k+3]);

        // ---- cooperative unit-stride store: 512 float4 per chunk ----
        // (lo ds_reads are lgkmcnt-waited before each store issues, so the
        // next iteration's DMA into this buffer can't race them.)
        float4* go = reinterpret_cast<float4*>(out) + chunk * 512;
#pragma unroll
        for (int c = 0; c < 8; c++) {
            const int g  = lane + 64 * c;
            const int p  = g >> 3;
            const int ch = g & 7;
            go[g] = *reinterpret_cast<const float4*>(lo + p * OSTRIDE + ch * 4);
        }

        // Fence: lo reads stay above anything the next iteration does.
        asm volatile("" ::: "memory");

        if (!pf) break;
        cur ^= 1;
        chunk = next;
    }
}

// Tail path (npts not divisible by 64) — scalar per-thread, same math.
__global__ __launch_bounds__(64)
void MVGeometricBilinear_tail(const float* __restrict__ x,
                              const float* __restrict__ y,
                              const float* __restrict__ ref,
                              float* __restrict__ out,
                              int start, int npts)
{
    int pt = start + blockIdx.x * 64 + threadIdx.x;
    if (pt >= npts) return;
    float xx[16], yy[16];
#pragma unroll
    for (int k = 0; k < 16; k++) { xx[k] = x[(size_t)pt*16+k]; yy[k] = y[(size_t)pt*16+k]; }
    const float r = ref[(size_t)pt*16+15];
    float gp[16] = {}, jn[16] = {};
#pragma unroll
    for (int t = 0; t < 192; t++) {
        const float v = xx[ga::G.t[t].i] * yy[ga::G.t[t].j];
        if (ga::G.t[t].s > 0) gp[ga::G.t[t].k] += v; else gp[ga::G.t[t].k] -= v;
    }
#pragma unroll
    for (int t = 0; t < 81; t++) {
        const float v = xx[ga::J.t[t].i] * yy[ga::J.t[t].j];
        if (ga::J.t[t].s > 0) jn[ga::J.t[t].k] += v; else jn[ga::J.t[t].k] -= v;
    }
#pragma unroll
    for (int k = 0; k < 16; k++) out[(size_t)pt*32+k] = gp[k];
#pragma unroll
    for (int k = 0; k < 16; k++) out[(size_t)pt*32+16+k] = r * jn[k];
}

extern "C" void kernel_launch(void* const* d_in, const int* in_sizes, int n_in,
                              void* d_out, int out_size, void* d_ws, size_t ws_size,
                              hipStream_t stream) {
    const float* x   = (const float*)d_in[0];
    const float* y   = (const float*)d_in[1];
    const float* ref = (const float*)d_in[2];
    float* out = (float*)d_out;

    const int npts    = in_sizes[0] / 16;     // B*T = 524288
    const int nchunks = npts / 64;            // 8192
    const int niter   = 4;                    // chunks per wave
    const int blocks  = (nchunks + niter - 1) / niter;   // 2048 = 8 blocks/CU

    if (nchunks > 0) {
        MVGeometricBilinear_kernel<<<blocks, 64, 0, stream>>>(
            x, y, ref, out, nchunks, niter);
    }

    const int rem = npts - nchunks * 64;      // 0 for this shape
    if (rem > 0) {
        MVGeometricBilinear_tail<<<(rem + 63) / 64, 64, 0, stream>>>(
            x, y, ref, out, nchunks * 64, npts);
    }
}